// Round 1
// baseline (329.215 us; speedup 1.0000x reference)
//
#include <hip/hip_runtime.h>

// Problem constants (fixed by setup_inputs)
#define BB   2
#define CCH  256
#define HH   200
#define WW   336
#define HWN  (HH * WW)
#define OH   7
#define OW   7
#define NSAMP 2
#define SCALEF 0.25f
#define NBIN (OH * OW)          // 49
#define PER_ROI (CCH * NBIN)    // 12544 floats per roi

// ---------------------------------------------------------------------------
// Kernel 1: transpose (B, C, H, W) -> (B, H*W, C)  (channels-last)
// Tiled 32x32 through LDS; HWN = 67200 = 32*2100 exactly, C = 256 = 32*8.
// ---------------------------------------------------------------------------
__global__ __launch_bounds__(256) void transpose_cl_k(const float* __restrict__ src,
                                                      float* __restrict__ dst) {
    __shared__ float tile[32][33];   // +1 pad: conflict-free transpose
    const int b   = blockIdx.z;
    const int hw0 = blockIdx.x * 32;
    const int c0  = blockIdx.y * 32;
    const int tx  = threadIdx.x;     // 0..31
    const int ty  = threadIdx.y;     // 0..7

#pragma unroll
    for (int i = 0; i < 4; ++i) {
        const int c = c0 + ty + i * 8;
        tile[ty + i * 8][tx] = src[(b * CCH + c) * HWN + hw0 + tx];   // coalesced read
    }
    __syncthreads();
#pragma unroll
    for (int i = 0; i < 4; ++i) {
        const int hw = hw0 + ty + i * 8;
        dst[(b * HWN + hw) * CCH + c0 + tx] = tile[tx][ty + i * 8];   // coalesced write
    }
}

// ---------------------------------------------------------------------------
// Kernel 2: RoIAlign. One block per roi; 256 threads = 256 channels.
// CL=true : features channels-last (B, H*W, C)  -> coalesced taps
// CL=false: features original (B, C, H, W)      -> fallback (correct, slow)
// ---------------------------------------------------------------------------
template <bool CL>
__global__ __launch_bounds__(256) void roi_align_k(const float* __restrict__ f,
                                                   const float* __restrict__ rois,
                                                   float* __restrict__ out) {
    const int n   = blockIdx.x;
    const int tid = threadIdx.x;
    const int c   = tid;

    __shared__ float buf[PER_ROI];                 // 50,176 B output staging
    __shared__ int   s_y0[NSAMP * OH], s_y1[NSAMP * OH];
    __shared__ int   s_x0[NSAMP * OW], s_x1[NSAMP * OW];
    __shared__ float s_ly[NSAMP * OH], s_lx[NSAMP * OW];
    __shared__ float s_vy[NSAMP * OH], s_vx[NSAMP * OW];

    const float* r = rois + n * 5;
    const int   b   = (int)r[0];
    const float rx1 = r[1] * SCALEF, ry1 = r[2] * SCALEF;
    const float rx2 = r[3] * SCALEF, ry2 = r[4] * SCALEF;
    const float roiw = fmaxf(rx2 - rx1, 1.0f);
    const float roih = fmaxf(ry2 - ry1, 1.0f);
    const float bw = roiw / OW, bh = roih / OH;

    // Precompute sample-line geometry (wave0: y lines, wave1: x lines)
    if (tid < NSAMP * OH) {
        const float ys = ry1 + ((float)tid + 0.5f) * (bh / NSAMP);
        const float vy = (ys >= -1.0f && ys <= (float)HH) ? 1.0f : 0.0f;
        const float y  = fminf(fmaxf(ys, 0.0f), (float)(HH - 1));
        const int y0   = (int)floorf(y);
        const int y1   = min(y0 + 1, HH - 1);
        s_y0[tid] = CL ? ((b * HH + y0) * WW) * CCH : y0 * WW;
        s_y1[tid] = CL ? ((b * HH + y1) * WW) * CCH : y1 * WW;
        s_ly[tid] = y - (float)y0;
        s_vy[tid] = vy;
    } else if (tid >= 64 && tid < 64 + NSAMP * OW) {
        const int j = tid - 64;
        const float xs = rx1 + ((float)j + 0.5f) * (bw / NSAMP);
        const float vx = (xs >= -1.0f && xs <= (float)WW) ? 1.0f : 0.0f;
        const float x  = fminf(fmaxf(xs, 0.0f), (float)(WW - 1));
        const int x0   = (int)floorf(x);
        const int x1   = min(x0 + 1, WW - 1);
        s_x0[j] = CL ? x0 * CCH : x0;
        s_x1[j] = CL ? x1 * CCH : x1;
        s_lx[j] = x - (float)x0;
        s_vx[j] = vx;
    }
    __syncthreads();

    const int tb = CL ? c : (b * CCH + c) * HWN;   // per-thread base offset

    for (int ph = 0; ph < OH; ++ph) {
        for (int pw = 0; pw < OW; ++pw) {
            float acc = 0.0f;
#pragma unroll
            for (int iy = 0; iy < NSAMP; ++iy) {
                const int py   = ph * NSAMP + iy;
                const int yb0  = s_y0[py], yb1 = s_y1[py];
                const float ly = s_ly[py], vy = s_vy[py];
                const float hy = 1.0f - ly;
#pragma unroll
                for (int ix = 0; ix < NSAMP; ++ix) {
                    const int px   = pw * NSAMP + ix;
                    const int xb0  = s_x0[px], xb1 = s_x1[px];
                    const float lx = s_lx[px], vx = s_vx[px];
                    const float hx = 1.0f - lx;
                    const float m  = vy * vx * 0.25f;   // mask + mean folded
                    const float f00 = f[tb + yb0 + xb0];
                    const float f01 = f[tb + yb0 + xb1];
                    const float f10 = f[tb + yb1 + xb0];
                    const float f11 = f[tb + yb1 + xb1];
                    acc += m * (hy * (hx * f00 + lx * f01) +
                                ly * (hx * f10 + lx * f11));
                }
            }
            // stride-49 LDS write: bank step 49%32=17, coprime with 32 -> conflict-free
            buf[c * NBIN + ph * OW + pw] = acc;
        }
    }
    __syncthreads();

    // Drain: out layout (N, C, OH, OW) is linear c*49+bin -> identical to buf's
    // linear layout, so a straight stride-1 copy is a fully coalesced store.
    const int base_out = n * PER_ROI;
    for (int i = tid; i < PER_ROI; i += 256) {
        out[base_out + i] = buf[i];
    }
}

extern "C" void kernel_launch(void* const* d_in, const int* in_sizes, int n_in,
                              void* d_out, int out_size, void* d_ws, size_t ws_size,
                              hipStream_t stream) {
    const float* feat = (const float*)d_in[0];
    const float* rois = (const float*)d_in[1];
    float* out = (float*)d_out;
    const int N = in_sizes[1] / 5;

    const size_t need = (size_t)BB * CCH * HWN * sizeof(float);   // 137.6 MB
    if (ws_size >= need) {
        float* fcl = (float*)d_ws;
        dim3 tb(32, 8);
        dim3 tg(HWN / 32, CCH / 32, BB);
        transpose_cl_k<<<tg, tb, 0, stream>>>(feat, fcl);
        roi_align_k<true><<<N, 256, 0, stream>>>(fcl, rois, out);
    } else {
        // workspace too small: direct-layout fallback (correct, uncoalesced)
        roi_align_k<false><<<N, 256, 0, stream>>>(feat, rois, out);
    }
}